// Round 3
// baseline (1424.903 us; speedup 1.0000x reference)
//
#include <hip/hip_runtime.h>

typedef unsigned short u16;
typedef __attribute__((ext_vector_type(8))) short bf16x8;
typedef __attribute__((ext_vector_type(4))) float floatx4;
typedef __attribute__((ext_vector_type(4))) unsigned short u16x4;

__device__ __forceinline__ float b2f(u16 u) {
  unsigned int i = ((unsigned int)u) << 16;
  return __builtin_bit_cast(float, i);
}
__device__ __forceinline__ u16 f2b(float f) {
  unsigned int i = __builtin_bit_cast(unsigned int, f);
  i += 0x7fffu + ((i >> 16) & 1u);
  return (u16)(i >> 16);
}
#define MFMA16(a, b, c) __builtin_amdgcn_mfma_f32_16x16x32_bf16((a), (b), (c), 0, 0, 0)

__device__ __forceinline__ void gload_lds16(const u16* g, u16* l) {
  __builtin_amdgcn_global_load_lds(
      (const __attribute__((address_space(1))) void*)g,
      (__attribute__((address_space(3))) void*)l, 16, 0, 0);
}

// pack 8 consecutive fp32 (two float4 loads) -> bf16x8
__device__ __forceinline__ bf16x8 load8_f32_as_bf16(const float* p) {
  float4 a = *(const float4*)p;
  float4 b = *(const float4*)(p + 4);
  bf16x8 r;
  r[0] = (short)f2b(a.x); r[1] = (short)f2b(a.y);
  r[2] = (short)f2b(a.z); r[3] = (short)f2b(a.w);
  r[4] = (short)f2b(b.x); r[5] = (short)f2b(b.y);
  r[6] = (short)f2b(b.z); r[7] = (short)f2b(b.w);
  return r;
}

// ---------------------------------------------------------------------------
// Kernel A: LayerNorm (shared mu/rsigma) + pos add, writes both branch layouts
// as bf16. yW[token] = LN(x;n3)+pos1[c]; yH[(b,c,r)] = LN(x;n4)+pos2[r]
// one wave per token (512 ch = 8 fp32 per lane)
// ---------------------------------------------------------------------------
__global__ __launch_bounds__(256) void ln_pos_kernel(
    const float* __restrict__ x, const float* __restrict__ n3w, const float* __restrict__ n3b,
    const float* __restrict__ n4w, const float* __restrict__ n4b,
    const float* __restrict__ pos1, const float* __restrict__ pos2,
    u16* __restrict__ yW, u16* __restrict__ yH) {
  int wv = threadIdx.x >> 6, lane = threadIdx.x & 63;
  int token = blockIdx.x * 4 + wv;
  int b = token >> 12, r = (token >> 6) & 63, c = token & 63;
  const float4* xr = (const float4*)(x + (size_t)token * 512) + lane * 2;
  float4 x0 = xr[0], x1 = xr[1];
  float v[8] = {x0.x, x0.y, x0.z, x0.w, x1.x, x1.y, x1.z, x1.w};
  float s = 0.f, ss = 0.f;
#pragma unroll
  for (int j = 0; j < 8; j++) { s += v[j]; ss += v[j] * v[j]; }
#pragma unroll
  for (int off = 1; off < 64; off <<= 1) { s += __shfl_xor(s, off); ss += __shfl_xor(ss, off); }
  float mu = s * (1.0f / 512.0f);
  float var = ss * (1.0f / 512.0f) - mu * mu;
  float rs = rsqrtf(var + 1e-5f);
  int ch0 = lane * 8;
  float w3[8], b3[8], w4[8], b4[8], p1[8], p2[8];
  *(float4*)&w3[0] = *(const float4*)(n3w + ch0); *(float4*)&w3[4] = *(const float4*)(n3w + ch0 + 4);
  *(float4*)&b3[0] = *(const float4*)(n3b + ch0); *(float4*)&b3[4] = *(const float4*)(n3b + ch0 + 4);
  *(float4*)&w4[0] = *(const float4*)(n4w + ch0); *(float4*)&w4[4] = *(const float4*)(n4w + ch0 + 4);
  *(float4*)&b4[0] = *(const float4*)(n4b + ch0); *(float4*)&b4[4] = *(const float4*)(n4b + ch0 + 4);
  const float* p1p = pos1 + (size_t)c * 512 + ch0;
  const float* p2p = pos2 + (size_t)r * 512 + ch0;
  *(float4*)&p1[0] = *(const float4*)p1p; *(float4*)&p1[4] = *(const float4*)(p1p + 4);
  *(float4*)&p2[0] = *(const float4*)p2p; *(float4*)&p2[4] = *(const float4*)(p2p + 4);
  bf16x8 ow, oh;
#pragma unroll
  for (int j = 0; j < 8; j++) {
    float xn = (v[j] - mu) * rs;
    ow[j] = (short)f2b(xn * w3[j] + b3[j] + p1[j]);
    oh[j] = (short)f2b(xn * w4[j] + b4[j] + p2[j]);
  }
  *(bf16x8*)(yW + (size_t)token * 512 + ch0) = ow;
  size_t hrow = (size_t)b * 4096 + (size_t)c * 64 + r;
  *(bf16x8*)(yH + hrow * 512 + ch0) = oh;
}

// ---------------------------------------------------------------------------
// Kernel B: QKV GEMM (m97 structure). Z[m,n] = sum_k y[m,k] * W[n,k]
// M=65536, K=512, N=1536. 128x128 tile, BK=32, 4 waves.
// A (bf16) staged via global_load_lds(16B); B (fp32 weights) staged via
// float4 loads + on-the-fly bf16 convert. grid (512, 12, 2)  z=branch
// ---------------------------------------------------------------------------
__global__ __launch_bounds__(256) void qkv_gemm_kernel(
    const u16* __restrict__ A0, const u16* __restrict__ A1,
    const float* __restrict__ W0, const float* __restrict__ W1,
    u16* __restrict__ Z0, u16* __restrict__ Z1) {
  const int K = 512, N = 1536;
  int br = blockIdx.z;
  const u16* A = br ? A1 : A0;
  const float* W = br ? W1 : W0;
  u16* Z = br ? Z1 : Z0;
  int m0 = blockIdx.x * 128, n0 = blockIdx.y * 128;
  __shared__ u16 As[128][32];
  __shared__ u16 Bs[128][32];
  int tid = threadIdx.x, lane = tid & 63, wave = tid >> 6;
  int wm = (wave >> 1) * 64, wn = (wave & 1) * 64;
  int ml = lane & 15, quad = lane >> 4;
  floatx4 acc[4][4];
#pragma unroll
  for (int mi = 0; mi < 4; mi++)
#pragma unroll
    for (int ni = 0; ni < 4; ni++) acc[mi][ni] = (floatx4){0.f, 0.f, 0.f, 0.f};

  int srow = (lane >> 2);          // 0..15 within 16-row chunk
  int scol = (lane & 3) * 8;       // element offset (16B)
  for (int kt = 0; kt < K; kt += 32) {
    // A: async 16B direct-to-LDS
#pragma unroll
    for (int i = 0; i < 2; i++) {
      int rbase = wave * 32 + i * 16;
      gload_lds16(A + (size_t)(m0 + rbase + srow) * K + kt + scol, &As[rbase][0]);
    }
    // B: fp32 -> bf16 on the fly (512 slots of 8 elements)
#pragma unroll
    for (int s = tid; s < 512; s += 256) {
      int rr = s >> 2, c0 = (s & 3) * 8;
      *(bf16x8*)&Bs[rr][c0] = load8_f32_as_bf16(W + (size_t)(n0 + rr) * K + kt + c0);
    }
    __syncthreads();
    bf16x8 a[4], bfr[4];
#pragma unroll
    for (int mi = 0; mi < 4; mi++) a[mi] = *(const bf16x8*)&As[wm + mi * 16 + ml][quad * 8];
#pragma unroll
    for (int ni = 0; ni < 4; ni++) bfr[ni] = *(const bf16x8*)&Bs[wn + ni * 16 + ml][quad * 8];
#pragma unroll
    for (int mi = 0; mi < 4; mi++)
#pragma unroll
      for (int ni = 0; ni < 4; ni++) acc[mi][ni] = MFMA16(a[mi], bfr[ni], acc[mi][ni]);
    __syncthreads();
  }
  // epilogue: C layout col=lane&15, row=quad*4+reg
#pragma unroll
  for (int mi = 0; mi < 4; mi++)
#pragma unroll
    for (int ni = 0; ni < 4; ni++) {
      int col = n0 + wn + ni * 16 + ml;
      int rbase = m0 + wm + mi * 16 + quad * 4;
#pragma unroll
      for (int r = 0; r < 4; r++) Z[(size_t)(rbase + r) * N + col] = f2b(acc[mi][ni][r]);
    }
}

// ---------------------------------------------------------------------------
// Shared attention core: 64x64 attention for one (window, head) tile.
// Qs/Ks row-major [64][72] (padded), Vt transposed [e][pos] [64][72].
// Each wave computes a 16-query strip; o[et] is C-layout (row=q, col=e).
// Psw = this wave's private 16x72 LDS scratch.
// ---------------------------------------------------------------------------
__device__ __forceinline__ void attn_core(const u16 (*Qs)[72], const u16 (*Ks)[72],
                                          const u16 (*Vt)[72], u16 (*Psw)[72],
                                          int wv, int lane, floatx4 o[4]) {
  int ml = lane & 15, quad = lane >> 4;
  bf16x8 aq0 = *(const bf16x8*)&Qs[wv * 16 + ml][quad * 8];
  bf16x8 aq1 = *(const bf16x8*)&Qs[wv * 16 + ml][32 + quad * 8];
  floatx4 s[4];
#pragma unroll
  for (int nt = 0; nt < 4; nt++) {
    floatx4 z = (floatx4){0.f, 0.f, 0.f, 0.f};
    bf16x8 b0 = *(const bf16x8*)&Ks[nt * 16 + ml][quad * 8];
    bf16x8 b1 = *(const bf16x8*)&Ks[nt * 16 + ml][32 + quad * 8];
    z = MFMA16(aq0, b0, z);
    z = MFMA16(aq1, b1, z);
    s[nt] = z;
  }
#pragma unroll
  for (int r = 0; r < 4; r++) {
    float m = -1e30f;
#pragma unroll
    for (int nt = 0; nt < 4; nt++) { s[nt][r] *= 0.125f; m = fmaxf(m, s[nt][r]); }
#pragma unroll
    for (int off = 1; off < 16; off <<= 1) m = fmaxf(m, __shfl_xor(m, off));
    float su = 0.f;
#pragma unroll
    for (int nt = 0; nt < 4; nt++) { float p = __expf(s[nt][r] - m); s[nt][r] = p; su += p; }
#pragma unroll
    for (int off = 1; off < 16; off <<= 1) su += __shfl_xor(su, off);
    float inv = 1.0f / su;
#pragma unroll
    for (int nt = 0; nt < 4; nt++) s[nt][r] *= inv;
  }
  // C-layout -> LDS -> A-layout round trip for P
#pragma unroll
  for (int nt = 0; nt < 4; nt++)
#pragma unroll
    for (int r = 0; r < 4; r++) Psw[quad * 4 + r][nt * 16 + ml] = f2b(s[nt][r]);
  __asm__ volatile("s_waitcnt lgkmcnt(0)" ::: "memory");
  bf16x8 ap0 = *(const bf16x8*)&Psw[ml][quad * 8];
  bf16x8 ap1 = *(const bf16x8*)&Psw[ml][32 + quad * 8];
#pragma unroll
  for (int et = 0; et < 4; et++) {
    floatx4 z = (floatx4){0.f, 0.f, 0.f, 0.f};
    bf16x8 b0 = *(const bf16x8*)&Vt[et * 16 + ml][quad * 8];
    bf16x8 b1 = *(const bf16x8*)&Vt[et * 16 + ml][32 + quad * 8];
    z = MFMA16(ap0, b0, z);
    z = MFMA16(ap1, b1, z);
    o[et] = z;
  }
}

// stage Q,K row-major + V transposed into LDS from Z tile (row stride 1536)
__device__ __forceinline__ void stage_qkv(const u16* Qg, const u16* Kg, const u16* Vg,
                                          u16 (*Qs)[72], u16 (*Ks)[72], u16 (*Vt)[72],
                                          int tid) {
  for (int i = tid; i < 512; i += 256) {
    int r = i >> 3, c = (i & 7) * 8;
    *(bf16x8*)&Qs[r][c] = *(const bf16x8*)(Qg + (size_t)r * 1536 + c);
    *(bf16x8*)&Ks[r][c] = *(const bf16x8*)(Kg + (size_t)r * 1536 + c);
  }
  for (int i = tid; i < 1024; i += 256) {
    int p = i >> 4, e0 = (i & 15) * 4;
    u16x4 v = *(const u16x4*)(Vg + (size_t)p * 1536 + e0);
    Vt[e0 + 0][p] = v.x; Vt[e0 + 1][p] = v.y; Vt[e0 + 2][p] = v.z; Vt[e0 + 3][p] = v.w;
  }
  __syncthreads();
}

// ---------------------------------------------------------------------------
// Kernel C: per-(window,head) attention + pos3/4 (fp32) + head-qkv (ln3/ln4 fp32,
// converted on the fly), results written IN-PLACE over the Q/K/V regions of Z.
// grid (1024, 8, 2)
// ---------------------------------------------------------------------------
__global__ __launch_bounds__(256) void attn_head_kernel(
    u16* __restrict__ Zw, u16* __restrict__ Zh,
    const float* __restrict__ lw3, const float* __restrict__ lw4,
    const float* __restrict__ pos3, const float* __restrict__ pos4) {
  int w = blockIdx.x, h = blockIdx.y, br = blockIdx.z;
  u16* Z = br ? Zh : Zw;
  const float* lw = br ? lw4 : lw3;
  const float* pp = br ? pos4 : pos3;
  __shared__ u16 Qs[64][72], Ks[64][72], Vt[64][72], Ps[4][16][72];
  int tid = threadIdx.x, lane = tid & 63, wv = tid >> 6;
  int ml = lane & 15, quad = lane >> 4;
  const u16* Qg = Z + (size_t)w * 64 * 1536 + h * 64;
  stage_qkv(Qg, Qg + 512, Qg + 1024, Qs, Ks, Vt, tid);
  floatx4 o[4];
  attn_core(Qs, Ks, Vt, Ps[wv], wv, lane, o);
  // x_ww = o + pos; back through LDS for A-layout
  const float* p3 = pp + (size_t)h * 64 * 64;
#pragma unroll
  for (int et = 0; et < 4; et++)
#pragma unroll
    for (int r = 0; r < 4; r++) {
      int qp = wv * 16 + quad * 4 + r, e = et * 16 + ml;
      Ps[wv][quad * 4 + r][et * 16 + ml] = f2b(o[et][r] + p3[(size_t)qp * 64 + e]);
    }
  __asm__ volatile("s_waitcnt lgkmcnt(0)" ::: "memory");
  bf16x8 ax0 = *(const bf16x8*)&Ps[wv][ml][quad * 8];
  bf16x8 ax1 = *(const bf16x8*)&Ps[wv][ml][32 + quad * 8];
#pragma unroll
  for (int nj = 0; nj < 12; nj++) {
    int col = nj * 16 + ml;
    const float* wrow = lw + (size_t)col * 64;
    bf16x8 b0 = load8_f32_as_bf16(wrow + quad * 8);
    bf16x8 b1 = load8_f32_as_bf16(wrow + 32 + quad * 8);
    floatx4 z = (floatx4){0.f, 0.f, 0.f, 0.f};
    z = MFMA16(ax0, b0, z);
    z = MFMA16(ax1, b1, z);
    int qk = col >> 6, e = col & 63;
    u16* dst = Z + (size_t)w * 64 * 1536 + (size_t)qk * 512 + h * 64 + e;
#pragma unroll
    for (int r = 0; r < 4; r++) dst[(size_t)(wv * 16 + quad * 4 + r) * 1536] = f2b(z[r]);
  }
}

// ---------------------------------------------------------------------------
// Kernel D: cross attention. z=0: o1=attn(xh_q, xw_k, xw_v) -> o1b
//                            z=1: o2=attn(xw_q, xh_k, xh_v) -> o2b
// output token-major bf16: ob[(w*64+qp)*512 + h*64 + e]. grid (1024, 8, 2)
// ---------------------------------------------------------------------------
__global__ __launch_bounds__(256) void cross_attn_kernel(
    const u16* __restrict__ Zw, const u16* __restrict__ Zh,
    u16* __restrict__ o1b, u16* __restrict__ o2b) {
  int w = blockIdx.x, h = blockIdx.y, which = blockIdx.z;
  const u16* Zq = which ? Zw : Zh;
  const u16* Zkv = which ? Zh : Zw;
  u16* ob = which ? o2b : o1b;
  __shared__ u16 Qs[64][72], Ks[64][72], Vt[64][72], Ps[4][16][72];
  int tid = threadIdx.x, lane = tid & 63, wv = tid >> 6;
  int ml = lane & 15, quad = lane >> 4;
  const u16* Qg = Zq + (size_t)w * 64 * 1536 + h * 64;
  const u16* Kg = Zkv + (size_t)w * 64 * 1536 + 512 + h * 64;
  const u16* Vg = Zkv + (size_t)w * 64 * 1536 + 1024 + h * 64;
  stage_qkv(Qg, Kg, Vg, Qs, Ks, Vt, tid);
  floatx4 o[4];
  attn_core(Qs, Ks, Vt, Ps[wv], wv, lane, o);
#pragma unroll
  for (int et = 0; et < 4; et++)
#pragma unroll
    for (int r = 0; r < 4; r++) {
      int qp = wv * 16 + quad * 4 + r, e = et * 16 + ml;
      ob[(size_t)(w * 64 + qp) * 512 + h * 64 + e] = f2b(o[et][r]);
    }
}

// ---------------------------------------------------------------------------
// Kernel E: out[token] = x[token] + o2b[token] + o1b[transposed token], fp32 out
// ---------------------------------------------------------------------------
__global__ __launch_bounds__(256) void final_add_kernel(
    const float* __restrict__ x, const u16* __restrict__ o1b,
    const u16* __restrict__ o2b, float* __restrict__ out) {
  int wv = threadIdx.x >> 6, lane = threadIdx.x & 63;
  int token = blockIdx.x * 4 + wv;
  int b = token >> 12, r = (token >> 6) & 63, c = token & 63;
  size_t i = (size_t)token * 512 + lane * 8;
  size_t i1 = ((size_t)b * 4096 + (size_t)c * 64 + r) * 512 + lane * 8;
  float vx[8];
  *(float4*)&vx[0] = *(const float4*)(x + i);
  *(float4*)&vx[4] = *(const float4*)(x + i + 4);
  bf16x8 v1 = *(const bf16x8*)(o1b + i1);
  bf16x8 v2 = *(const bf16x8*)(o2b + i);
  float vo[8];
#pragma unroll
  for (int j = 0; j < 8; j++)
    vo[j] = vx[j] + b2f((u16)v1[j]) + b2f((u16)v2[j]);
  *(float4*)(out + i) = *(float4*)&vo[0];
  *(float4*)(out + i + 4) = *(float4*)&vo[4];
}

extern "C" void kernel_launch(void* const* d_in, const int* in_sizes, int n_in,
                              void* d_out, int out_size, void* d_ws, size_t ws_size,
                              hipStream_t stream) {
  const float* x    = (const float*)d_in[0];
  const float* n3w  = (const float*)d_in[1];
  const float* n3b  = (const float*)d_in[2];
  const float* n4w  = (const float*)d_in[3];
  const float* n4b  = (const float*)d_in[4];
  const float* ln1  = (const float*)d_in[5];
  const float* ln2  = (const float*)d_in[6];
  const float* ln3  = (const float*)d_in[7];
  const float* ln4  = (const float*)d_in[8];
  const float* pos1 = (const float*)d_in[9];
  const float* pos2 = (const float*)d_in[10];
  const float* pos3 = (const float*)d_in[11];
  const float* pos4 = (const float*)d_in[12];

  // workspace: exactly 512 MiB (the round-1 footprint that ran in-bounds)
  char* ws = (char*)d_ws;
  u16* yW = (u16*)ws;                                  //  64 MiB (65536x512 bf16)
  u16* yH = (u16*)(ws + (size_t)67108864);             //  64 MiB
  u16* Zw = (u16*)(ws + (size_t)134217728);            // 192 MiB (65536x1536 bf16)
  u16* Zh = (u16*)(ws + (size_t)335544320);            // 192 MiB  (end = 512 MiB)
  u16* o1b = yW;                                       // alias: y consumed by GEMM
  u16* o2b = yH;
  float* out = (float*)d_out;

  ln_pos_kernel<<<16384, 256, 0, stream>>>(x, n3w, n3b, n4w, n4b, pos1, pos2, yW, yH);
  qkv_gemm_kernel<<<dim3(512, 12, 2), 256, 0, stream>>>(yW, yH, ln1, ln2, Zw, Zh);
  attn_head_kernel<<<dim3(1024, 8, 2), 256, 0, stream>>>(Zw, Zh, ln3, ln4, pos3, pos4);
  cross_attn_kernel<<<dim3(1024, 8, 2), 256, 0, stream>>>(Zw, Zh, o1b, o2b);
  final_add_kernel<<<16384, 256, 0, stream>>>(x, o1b, o2b, out);
}

// Round 4
// 1044.786 us; speedup vs baseline: 1.3638x; 1.3638x over previous
//
#include <hip/hip_runtime.h>

typedef unsigned short u16;
typedef __attribute__((ext_vector_type(8))) short bf16x8;
typedef __attribute__((ext_vector_type(4))) float floatx4;
typedef __attribute__((ext_vector_type(4))) unsigned short u16x4;

__device__ __forceinline__ float b2f(u16 u) {
  unsigned int i = ((unsigned int)u) << 16;
  return __builtin_bit_cast(float, i);
}
__device__ __forceinline__ u16 f2b(float f) {
  unsigned int i = __builtin_bit_cast(unsigned int, f);
  i += 0x7fffu + ((i >> 16) & 1u);
  return (u16)(i >> 16);
}
#define MFMA16(a, b, c) __builtin_amdgcn_mfma_f32_16x16x32_bf16((a), (b), (c), 0, 0, 0)
#define LGKM0() __asm__ volatile("s_waitcnt lgkmcnt(0)" ::: "memory")

__device__ __forceinline__ void gload_lds16(const u16* g, u16* l) {
  __builtin_amdgcn_global_load_lds(
      (const __attribute__((address_space(1))) void*)g,
      (__attribute__((address_space(3))) void*)l, 16, 0, 0);
}

// ---------------------------------------------------------------------------
// Kernel 0: fp32 -> bf16 conversion (weights; scratch lives in d_out)
// ---------------------------------------------------------------------------
__global__ __launch_bounds__(256) void cvt_kernel(const float* __restrict__ a,
                                                  u16* __restrict__ o, int n4) {
  int i = blockIdx.x * 256 + threadIdx.x;
  if (i < n4) {
    float4 v = ((const float4*)a)[i];
    u16x4 r;
    r.x = f2b(v.x); r.y = f2b(v.y); r.z = f2b(v.z); r.w = f2b(v.w);
    ((u16x4*)o)[i] = r;
  }
}

// ---------------------------------------------------------------------------
// Kernel A: LayerNorm (shared mu/rsigma) + pos add -> both branch layouts, bf16
// ---------------------------------------------------------------------------
__global__ __launch_bounds__(256) void ln_pos_kernel(
    const float* __restrict__ x, const float* __restrict__ n3w, const float* __restrict__ n3b,
    const float* __restrict__ n4w, const float* __restrict__ n4b,
    const float* __restrict__ pos1, const float* __restrict__ pos2,
    u16* __restrict__ yW, u16* __restrict__ yH) {
  int wv = threadIdx.x >> 6, lane = threadIdx.x & 63;
  int token = blockIdx.x * 4 + wv;
  int b = token >> 12, r = (token >> 6) & 63, c = token & 63;
  const float4* xr = (const float4*)(x + (size_t)token * 512) + lane * 2;
  float4 x0 = xr[0], x1 = xr[1];
  float v[8] = {x0.x, x0.y, x0.z, x0.w, x1.x, x1.y, x1.z, x1.w};
  float s = 0.f, ss = 0.f;
#pragma unroll
  for (int j = 0; j < 8; j++) { s += v[j]; ss += v[j] * v[j]; }
#pragma unroll
  for (int off = 1; off < 64; off <<= 1) { s += __shfl_xor(s, off); ss += __shfl_xor(ss, off); }
  float mu = s * (1.0f / 512.0f);
  float var = ss * (1.0f / 512.0f) - mu * mu;
  float rs = rsqrtf(var + 1e-5f);
  int ch0 = lane * 8;
  float w3[8], b3[8], w4[8], b4[8], p1[8], p2[8];
  *(float4*)&w3[0] = *(const float4*)(n3w + ch0); *(float4*)&w3[4] = *(const float4*)(n3w + ch0 + 4);
  *(float4*)&b3[0] = *(const float4*)(n3b + ch0); *(float4*)&b3[4] = *(const float4*)(n3b + ch0 + 4);
  *(float4*)&w4[0] = *(const float4*)(n4w + ch0); *(float4*)&w4[4] = *(const float4*)(n4w + ch0 + 4);
  *(float4*)&b4[0] = *(const float4*)(n4b + ch0); *(float4*)&b4[4] = *(const float4*)(n4b + ch0 + 4);
  const float* p1p = pos1 + (size_t)c * 512 + ch0;
  const float* p2p = pos2 + (size_t)r * 512 + ch0;
  *(float4*)&p1[0] = *(const float4*)p1p; *(float4*)&p1[4] = *(const float4*)(p1p + 4);
  *(float4*)&p2[0] = *(const float4*)p2p; *(float4*)&p2[4] = *(const float4*)(p2p + 4);
  bf16x8 ow, oh;
#pragma unroll
  for (int j = 0; j < 8; j++) {
    float xn = (v[j] - mu) * rs;
    ow[j] = (short)f2b(xn * w3[j] + b3[j] + p1[j]);
    oh[j] = (short)f2b(xn * w4[j] + b4[j] + p2[j]);
  }
  *(bf16x8*)(yW + (size_t)token * 512 + ch0) = ow;
  size_t hrow = (size_t)b * 4096 + (size_t)c * 64 + r;
  *(bf16x8*)(yH + hrow * 512 + ch0) = oh;
}

// ---------------------------------------------------------------------------
// Kernel B: QKV GEMM, m97 structure, all-bf16 staging via global_load_lds(16B),
// coalesced epilogue via per-wave LDS transpose. grid (12, 512, 2) n-fastest.
// ---------------------------------------------------------------------------
__global__ __launch_bounds__(256) void qkv_gemm_kernel(
    const u16* __restrict__ A0, const u16* __restrict__ A1,
    const u16* __restrict__ W0, const u16* __restrict__ W1,
    u16* __restrict__ Z0, u16* __restrict__ Z1) {
  const int K = 512, N = 1536;
  int br = blockIdx.z;
  const u16* A = br ? A1 : A0;
  const u16* W = br ? W1 : W0;
  u16* Z = br ? Z1 : Z0;
  int n0 = blockIdx.x * 128, m0 = blockIdx.y * 128;
  __shared__ u16 gpool[8192];                 // As[128][32] | Bs[128][32]
  u16 (*As)[32] = (u16(*)[32])gpool;
  u16 (*Bs)[32] = (u16(*)[32])(gpool + 4096);
  int tid = threadIdx.x, lane = tid & 63, wave = tid >> 6;
  int wm = (wave >> 1) * 64, wn = (wave & 1) * 64;
  int ml = lane & 15, quad = lane >> 4;
  floatx4 acc[4][4];
#pragma unroll
  for (int mi = 0; mi < 4; mi++)
#pragma unroll
    for (int ni = 0; ni < 4; ni++) acc[mi][ni] = (floatx4){0.f, 0.f, 0.f, 0.f};

  int srow = (lane >> 2);          // 0..15 within 16-row chunk
  int scol = (lane & 3) * 8;       // element offset (16B)
  for (int kt = 0; kt < K; kt += 32) {
#pragma unroll
    for (int i = 0; i < 2; i++) {
      int rbase = wave * 32 + i * 16;
      gload_lds16(A + (size_t)(m0 + rbase + srow) * K + kt + scol, &As[rbase][0]);
      gload_lds16(W + (size_t)(n0 + rbase + srow) * K + kt + scol, &Bs[rbase][0]);
    }
    __syncthreads();
    bf16x8 a[4], bfr[4];
#pragma unroll
    for (int mi = 0; mi < 4; mi++) a[mi] = *(const bf16x8*)&As[wm + mi * 16 + ml][quad * 8];
#pragma unroll
    for (int ni = 0; ni < 4; ni++) bfr[ni] = *(const bf16x8*)&Bs[wn + ni * 16 + ml][quad * 8];
#pragma unroll
    for (int mi = 0; mi < 4; mi++)
#pragma unroll
      for (int ni = 0; ni < 4; ni++) acc[mi][ni] = MFMA16(a[mi], bfr[ni], acc[mi][ni]);
    __syncthreads();
  }
  // epilogue: per-wave LDS transpose -> bf16x8 coalesced stores.
  // wave-private region: 2048 u16 (= 32 rows x 64 cols)
  u16* wl = gpool + wave * 2048;
#pragma unroll
  for (int pair = 0; pair < 2; pair++) {
#pragma unroll
    for (int mh = 0; mh < 2; mh++) {
      int mi = pair * 2 + mh;
#pragma unroll
      for (int ni = 0; ni < 4; ni++)
#pragma unroll
        for (int r = 0; r < 4; r++)
          wl[(mh * 16 + quad * 4 + r) * 64 + ni * 16 + ml] = f2b(acc[mi][ni][r]);
    }
    LGKM0();
#pragma unroll
    for (int p = 0; p < 4; p++) {
      int lrow = p * 8 + (lane >> 3);
      int col8 = (lane & 7) * 8;
      bf16x8 vv = *(const bf16x8*)&wl[lrow * 64 + col8];
      int rg = m0 + wm + pair * 32 + lrow;
      *(bf16x8*)&Z[(size_t)rg * N + n0 + wn + col8] = vv;
    }
    LGKM0();
  }
}

// ---------------------------------------------------------------------------
// Shared attention core: 64x64 attention for one (window, head) tile.
// ---------------------------------------------------------------------------
__device__ __forceinline__ void attn_core(const u16 (*Qs)[72], const u16 (*Ks)[72],
                                          const u16 (*Vt)[72], u16 (*Psw)[72],
                                          int wv, int lane, floatx4 o[4]) {
  int ml = lane & 15, quad = lane >> 4;
  bf16x8 aq0 = *(const bf16x8*)&Qs[wv * 16 + ml][quad * 8];
  bf16x8 aq1 = *(const bf16x8*)&Qs[wv * 16 + ml][32 + quad * 8];
  floatx4 s[4];
#pragma unroll
  for (int nt = 0; nt < 4; nt++) {
    floatx4 z = (floatx4){0.f, 0.f, 0.f, 0.f};
    bf16x8 b0 = *(const bf16x8*)&Ks[nt * 16 + ml][quad * 8];
    bf16x8 b1 = *(const bf16x8*)&Ks[nt * 16 + ml][32 + quad * 8];
    z = MFMA16(aq0, b0, z);
    z = MFMA16(aq1, b1, z);
    s[nt] = z;
  }
#pragma unroll
  for (int r = 0; r < 4; r++) {
    float m = -1e30f;
#pragma unroll
    for (int nt = 0; nt < 4; nt++) { s[nt][r] *= 0.125f; m = fmaxf(m, s[nt][r]); }
#pragma unroll
    for (int off = 1; off < 16; off <<= 1) m = fmaxf(m, __shfl_xor(m, off));
    float su = 0.f;
#pragma unroll
    for (int nt = 0; nt < 4; nt++) { float p = __expf(s[nt][r] - m); s[nt][r] = p; su += p; }
#pragma unroll
    for (int off = 1; off < 16; off <<= 1) su += __shfl_xor(su, off);
    float inv = 1.0f / su;
#pragma unroll
    for (int nt = 0; nt < 4; nt++) s[nt][r] *= inv;
  }
#pragma unroll
  for (int nt = 0; nt < 4; nt++)
#pragma unroll
    for (int r = 0; r < 4; r++) Psw[quad * 4 + r][nt * 16 + ml] = f2b(s[nt][r]);
  LGKM0();
  bf16x8 ap0 = *(const bf16x8*)&Psw[ml][quad * 8];
  bf16x8 ap1 = *(const bf16x8*)&Psw[ml][32 + quad * 8];
#pragma unroll
  for (int et = 0; et < 4; et++) {
    floatx4 z = (floatx4){0.f, 0.f, 0.f, 0.f};
    bf16x8 b0 = *(const bf16x8*)&Vt[et * 16 + ml][quad * 8];
    bf16x8 b1 = *(const bf16x8*)&Vt[et * 16 + ml][32 + quad * 8];
    z = MFMA16(ap0, b0, z);
    z = MFMA16(ap1, b1, z);
    o[et] = z;
  }
}

// stage Q,K row-major + V transposed into LDS from Z tile (row stride 1536)
__device__ __forceinline__ void stage_qkv(const u16* Qg, const u16* Kg, const u16* Vg,
                                          u16 (*Qs)[72], u16 (*Ks)[72], u16 (*Vt)[72],
                                          int tid) {
  for (int i = tid; i < 512; i += 256) {
    int r = i >> 3, c = (i & 7) * 8;
    *(bf16x8*)&Qs[r][c] = *(const bf16x8*)(Qg + (size_t)r * 1536 + c);
    *(bf16x8*)&Ks[r][c] = *(const bf16x8*)(Kg + (size_t)r * 1536 + c);
  }
  for (int i = tid; i < 1024; i += 256) {
    int p = i >> 4, e0 = (i & 15) * 4;
    u16x4 v = *(const u16x4*)(Vg + (size_t)p * 1536 + e0);
    Vt[e0 + 0][p] = v.x; Vt[e0 + 1][p] = v.y; Vt[e0 + 2][p] = v.z; Vt[e0 + 3][p] = v.w;
  }
  __syncthreads();
}

// ---------------------------------------------------------------------------
// Kernel C: per-(window,head) attention + pos3/4 + head-qkv (bf16 weights),
// written IN-PLACE over Q/K/V regions of Z via LDS-staged coalesced stores.
// ---------------------------------------------------------------------------
__global__ __launch_bounds__(256) void attn_head_kernel(
    u16* __restrict__ Zw, u16* __restrict__ Zh,
    const u16* __restrict__ l3b, const u16* __restrict__ l4b,
    const float* __restrict__ pos3, const float* __restrict__ pos4) {
  int w = blockIdx.x, h = blockIdx.y, br = blockIdx.z;
  u16* Z = br ? Zh : Zw;
  const u16* lw = br ? l4b : l3b;
  const float* pp = br ? pos4 : pos3;
  __shared__ u16 pool[18432];                 // Qs|Ks|Vt|Ps ; Out overlays Qs..Vt
  u16 (*Qs)[72] = (u16(*)[72])pool;
  u16 (*Ks)[72] = (u16(*)[72])(pool + 4608);
  u16 (*Vt)[72] = (u16(*)[72])(pool + 9216);
  u16* Out = pool;                            // 64 x 192 = 12288 u16
  int tid = threadIdx.x, lane = tid & 63, wv = tid >> 6;
  int ml = lane & 15, quad = lane >> 4;
  u16 (*Ps)[72] = (u16(*)[72])(pool + 13824 + wv * 16 * 72);
  const u16* Qg = Z + (size_t)w * 64 * 1536 + h * 64;
  stage_qkv(Qg, Qg + 512, Qg + 1024, Qs, Ks, Vt, tid);
  floatx4 o[4];
  attn_core(Qs, Ks, Vt, Ps, wv, lane, o);
  // x_ww = o + pos; back through LDS (per-wave Ps) for A-layout
  const float* p3 = pp + (size_t)h * 64 * 64;
#pragma unroll
  for (int et = 0; et < 4; et++)
#pragma unroll
    for (int r = 0; r < 4; r++) {
      int qp = wv * 16 + quad * 4 + r, e = et * 16 + ml;
      Ps[quad * 4 + r][et * 16 + ml] = f2b(o[et][r] + p3[(size_t)qp * 64 + e]);
    }
  LGKM0();
  bf16x8 ax0 = *(const bf16x8*)&Ps[ml][quad * 8];
  bf16x8 ax1 = *(const bf16x8*)&Ps[ml][32 + quad * 8];
  __syncthreads();   // all waves done with Qs/Ks/Vt -> Out may overlay
#pragma unroll
  for (int nj = 0; nj < 12; nj++) {
    int col = nj * 16 + ml;
    bf16x8 b0 = *(const bf16x8*)(lw + (size_t)col * 64 + quad * 8);
    bf16x8 b1 = *(const bf16x8*)(lw + (size_t)col * 64 + 32 + quad * 8);
    floatx4 z = (floatx4){0.f, 0.f, 0.f, 0.f};
    z = MFMA16(ax0, b0, z);
    z = MFMA16(ax1, b1, z);
#pragma unroll
    for (int r = 0; r < 4; r++)
      Out[(wv * 16 + quad * 4 + r) * 192 + nj * 16 + ml] = f2b(z[r]);
  }
  __syncthreads();
  // bulk store: 1536 chunks of 16B, 128B segments per (pos,qk)
  u16* Zb = Z + (size_t)w * 64 * 1536 + h * 64;
#pragma unroll
  for (int j = 0; j < 6; j++) {
    int c = tid + j * 256;
    int pos = c / 24, cc = (c % 24) * 8;
    int qk = cc >> 6, e = cc & 63;
    bf16x8 vv = *(const bf16x8*)&Out[pos * 192 + cc];
    *(bf16x8*)&Zb[(size_t)pos * 1536 + (size_t)qk * 512 + e] = vv;
  }
}

// ---------------------------------------------------------------------------
// Kernel D: cross attention -> token-major bf16 out via LDS-staged stores.
// ---------------------------------------------------------------------------
__global__ __launch_bounds__(256) void cross_attn_kernel(
    const u16* __restrict__ Zw, const u16* __restrict__ Zh,
    u16* __restrict__ o1b, u16* __restrict__ o2b) {
  int w = blockIdx.x, h = blockIdx.y, which = blockIdx.z;
  const u16* Zq = which ? Zw : Zh;
  const u16* Zkv = which ? Zh : Zw;
  u16* ob = which ? o2b : o1b;
  __shared__ u16 pool[18432];
  u16 (*Qs)[72] = (u16(*)[72])pool;
  u16 (*Ks)[72] = (u16(*)[72])(pool + 4608);
  u16 (*Vt)[72] = (u16(*)[72])(pool + 9216);
  u16* Out = pool;                            // 64 x 64 = 4096 u16
  int tid = threadIdx.x, lane = tid & 63, wv = tid >> 6;
  int ml = lane & 15, quad = lane >> 4;
  u16 (*Ps)[72] = (u16(*)[72])(pool + 13824 + wv * 16 * 72);
  const u16* Qg = Zq + (size_t)w * 64 * 1536 + h * 64;
  const u16* Kg = Zkv + (size_t)w * 64 * 1536 + 512 + h * 64;
  const u16* Vg = Zkv + (size_t)w * 64 * 1536 + 1024 + h * 64;
  stage_qkv(Qg, Kg, Vg, Qs, Ks, Vt, tid);
  floatx4 o[4];
  attn_core(Qs, Ks, Vt, Ps, wv, lane, o);
  __syncthreads();   // all waves done with Qs/Ks/Vt
#pragma unroll
  for (int et = 0; et < 4; et++)
#pragma unroll
    for (int r = 0; r < 4; r++)
      Out[(wv * 16 + quad * 4 + r) * 64 + et * 16 + ml] = f2b(o[et][r]);
  __syncthreads();
  u16* obb = ob + (size_t)w * 64 * 512 + h * 64;
#pragma unroll
  for (int j = 0; j < 2; j++) {
    int c = tid + j * 256;
    int pos = c >> 3, cc = (c & 7) * 8;
    bf16x8 vv = *(const bf16x8*)&Out[pos * 64 + cc];
    *(bf16x8*)&obb[(size_t)pos * 512 + cc] = vv;
  }
}

// ---------------------------------------------------------------------------
// Kernel E: out[token] = x[token] + o2b[token] + o1b[transposed token], fp32
// ---------------------------------------------------------------------------
__global__ __launch_bounds__(256) void final_add_kernel(
    const float* __restrict__ x, const u16* __restrict__ o1b,
    const u16* __restrict__ o2b, float* __restrict__ out) {
  int wv = threadIdx.x >> 6, lane = threadIdx.x & 63;
  int token = blockIdx.x * 4 + wv;
  int b = token >> 12, r = (token >> 6) & 63, c = token & 63;
  size_t i = (size_t)token * 512 + lane * 8;
  size_t i1 = ((size_t)b * 4096 + (size_t)c * 64 + r) * 512 + lane * 8;
  float vx[8];
  *(float4*)&vx[0] = *(const float4*)(x + i);
  *(float4*)&vx[4] = *(const float4*)(x + i + 4);
  bf16x8 v1 = *(const bf16x8*)(o1b + i1);
  bf16x8 v2 = *(const bf16x8*)(o2b + i);
  float vo[8];
#pragma unroll
  for (int j = 0; j < 8; j++)
    vo[j] = vx[j] + b2f((u16)v1[j]) + b2f((u16)v2[j]);
  *(float4*)(out + i) = *(float4*)&vo[0];
  *(float4*)(out + i + 4) = *(float4*)&vo[4];
}

extern "C" void kernel_launch(void* const* d_in, const int* in_sizes, int n_in,
                              void* d_out, int out_size, void* d_ws, size_t ws_size,
                              hipStream_t stream) {
  const float* x    = (const float*)d_in[0];
  const float* n3w  = (const float*)d_in[1];
  const float* n3b  = (const float*)d_in[2];
  const float* n4w  = (const float*)d_in[3];
  const float* n4b  = (const float*)d_in[4];
  const float* ln1  = (const float*)d_in[5];
  const float* ln2  = (const float*)d_in[6];
  const float* ln3  = (const float*)d_in[7];
  const float* ln4  = (const float*)d_in[8];
  const float* pos1 = (const float*)d_in[9];
  const float* pos2 = (const float*)d_in[10];
  const float* pos3 = (const float*)d_in[11];
  const float* pos4 = (const float*)d_in[12];

  // workspace: exactly 512 MiB (proven-safe footprint)
  char* ws = (char*)d_ws;
  u16* yW = (u16*)ws;                                  //  64 MiB (65536x512 bf16)
  u16* yH = (u16*)(ws + (size_t)67108864);             //  64 MiB
  u16* Zw = (u16*)(ws + (size_t)134217728);            // 192 MiB (65536x1536 bf16)
  u16* Zh = (u16*)(ws + (size_t)335544320);            // 192 MiB  (end = 512 MiB)
  u16* o1b = yW;                                       // alias: y consumed by GEMM
  u16* o2b = yH;
  float* out = (float*)d_out;

  // bf16 weight copies live in d_out (3 MiB of 128 MiB); final_add overwrites.
  u16* Wb1 = (u16*)d_out;            // 1536x512
  u16* Wb2 = Wb1 + 786432;
  u16* l3b = Wb2 + 786432;           // 192x64
  u16* l4b = l3b + 12288;

  cvt_kernel<<<768, 256, 0, stream>>>(ln1, Wb1, 196608);
  cvt_kernel<<<768, 256, 0, stream>>>(ln2, Wb2, 196608);
  cvt_kernel<<<12, 256, 0, stream>>>(ln3, l3b, 3072);
  cvt_kernel<<<12, 256, 0, stream>>>(ln4, l4b, 3072);
  ln_pos_kernel<<<16384, 256, 0, stream>>>(x, n3w, n3b, n4w, n4b, pos1, pos2, yW, yH);
  qkv_gemm_kernel<<<dim3(12, 512, 2), 256, 0, stream>>>(yW, yH, Wb1, Wb2, Zw, Zh);
  attn_head_kernel<<<dim3(1024, 8, 2), 256, 0, stream>>>(Zw, Zh, l3b, l4b, pos3, pos4);
  cross_attn_kernel<<<dim3(1024, 8, 2), 256, 0, stream>>>(Zw, Zh, o1b, o2b);
  final_add_kernel<<<16384, 256, 0, stream>>>(x, o1b, o2b, out);
}